// Round 10
// baseline (311.701 us; speedup 1.0000x reference)
//
#include <hip/hip_runtime.h>

#define HW 129600
#define WG 360
#define HG 360
#define NCLS 10
#define NPROP 200
#define CDIM 128
#define NROWS 80000
#define NB 2
#define NPB (NROWS / NB)    // rows are batch-sorted: row<40000 -> b=0
#define SEL_CAP 4096
#define HBINS 4096          // heat in (0,1]: (bits>>18) <= 4064
#define RPB 64              // rows per k_head block
#define PSTR 12             // row stride (floats): 10 classes + 2 pad, 48B
#define TGRID 256           // tail grid: 1 block/CU needed, >=2/CU capacity
#define TBLK 1024           // tail block threads (16 waves/CU = 50% occ)
#define NTILE 625           // 80000/128 NMS tiles (8 thr/row x 128 rows)
#define CTILE 79            // ceil(80000/1024) collect tiles
#define REG 96              // sel slots per (batch, collect tile); E[hits]~10
#define DPART 128           // phase-D parts per batch (TGRID = NB*DPART)

// ---------------------------------------------------------------------------
// Async global->LDS DMA, 16B per lane; LDS dest wave-uniform base (m97/m104).
// ---------------------------------------------------------------------------
__device__ __forceinline__ void lds_cp16(float* l, const float* g) {
  __builtin_amdgcn_global_load_lds(
      (const __attribute__((address_space(1))) void*)g,
      (__attribute__((address_space(3))) void*)l, 16, 0, 0);
}

// Software grid barrier (normal launch; all TGRID blocks co-resident by
// construction). Producer release fence -> device-scope arrive; spinner uses
// RMW reads (coherence point) + s_sleep backoff; acquire fence on ALL threads.
__device__ __forceinline__ void gbar(int* ctr) {
  __syncthreads();
  if (threadIdx.x == 0) {
    __threadfence();
    atomicAdd(ctr, 1);
    while (atomicAdd(ctr, 0) < TGRID) __builtin_amdgcn_s_sleep(8);
  }
  __syncthreads();
  __threadfence();
}

// ---------------------------------------------------------------------------
// K1: fused MLP head (unchanged — bit-exact heat). Block 0 zeroes hist,
// cnts and the barrier counters (stream-ordered before k_tail).
// ---------------------------------------------------------------------------
__global__ __launch_bounds__(256, 4) void k_head(
    const float* __restrict__ feat, const float* __restrict__ W1,
    const float* __restrict__ b1, const float* __restrict__ W2,
    const float* __restrict__ b2, const int* __restrict__ idxs,
    float* __restrict__ val_raw, int* __restrict__ rowmap,
    unsigned int* __restrict__ hist, int* __restrict__ cnts,
    int* __restrict__ bar) {
  __shared__ __align__(16) float lds_w[2][16 * 128];  // 16KB: W1 chunks
  __shared__ __align__(16) float lds_f[2][RPB * 16];  // 8KB: f chunks; W2^T later
  const int tid = threadIdx.x;
  const int row0 = blockIdx.x * RPB;
  const int tc = tid & 31;
  const int tr = tid >> 5;
  const int wv = tid >> 6;  // wave id (uniform within wave)
  const int lane = tid & 63;

  auto stage = [&](int kt, int nb) {
#pragma unroll
    for (int c = 0; c < 2; ++c) {
      const int off = (wv * 2 + c) * 256;  // wave-uniform float offset
      lds_cp16(&lds_w[nb][off], W1 + kt * 2048 + off + lane * 4);
    }
    {
      const int off = wv * 256;
      const int fidx = off + lane * 4;
      const int r = fidx >> 4, kk = fidx & 15;
      lds_cp16(&lds_f[nb][off],
               feat + (size_t)(row0 + r) * CDIM + kt * 16 + kk);
    }
  };

  stage(0, 0);
  if (blockIdx.x == 0) {  // replaces memset dispatches
    uint4* h4 = (uint4*)hist;
    for (int i = tid; i < (NB * HBINS) / 4; i += 256)
      h4[i] = make_uint4(0u, 0u, 0u, 0u);
    for (int i = tid; i < NB * CTILE; i += 256) cnts[i] = 0;
    if (tid < 2) bar[tid] = 0;
  }
  if (tid < RPB) {
    int row = row0 + tid;
    int bb = idxs[row * 3 + 0];
    int yy = idxs[row * 3 + 1];
    int xx = idxs[row * 3 + 2];
    rowmap[(size_t)bb * HW + yy * WG + xx] = row;
  }
  __syncthreads();

  float acc[8][4];
#pragma unroll
  for (int r = 0; r < 8; ++r)
#pragma unroll
    for (int c = 0; c < 4; ++c) acc[r][c] = 0.f;

  for (int kt = 0; kt < 8; ++kt) {
    const int cb = kt & 1;
    if (kt < 7) stage(kt + 1, cb ^ 1);  // async; lands during compute
#pragma unroll
    for (int kg = 0; kg < 4; ++kg) {
      float4 w0 = *(const float4*)(&lds_w[cb][(kg * 4 + 0) * 128 + tc * 4]);
      float4 w1 = *(const float4*)(&lds_w[cb][(kg * 4 + 1) * 128 + tc * 4]);
      float4 w2 = *(const float4*)(&lds_w[cb][(kg * 4 + 2) * 128 + tc * 4]);
      float4 w3 = *(const float4*)(&lds_w[cb][(kg * 4 + 3) * 128 + tc * 4]);
#pragma unroll
      for (int r = 0; r < 8; ++r) {
        float4 fv = *(const float4*)(&lds_f[cb][(tr * 8 + r) * 16 + kg * 4]);
        acc[r][0] = fmaf(fv.x, w0.x, acc[r][0]);
        acc[r][0] = fmaf(fv.y, w1.x, acc[r][0]);
        acc[r][0] = fmaf(fv.z, w2.x, acc[r][0]);
        acc[r][0] = fmaf(fv.w, w3.x, acc[r][0]);
        acc[r][1] = fmaf(fv.x, w0.y, acc[r][1]);
        acc[r][1] = fmaf(fv.y, w1.y, acc[r][1]);
        acc[r][1] = fmaf(fv.z, w2.y, acc[r][1]);
        acc[r][1] = fmaf(fv.w, w3.y, acc[r][1]);
        acc[r][2] = fmaf(fv.x, w0.z, acc[r][2]);
        acc[r][2] = fmaf(fv.y, w1.z, acc[r][2]);
        acc[r][2] = fmaf(fv.z, w2.z, acc[r][2]);
        acc[r][2] = fmaf(fv.w, w3.z, acc[r][2]);
        acc[r][3] = fmaf(fv.x, w0.w, acc[r][3]);
        acc[r][3] = fmaf(fv.y, w1.w, acc[r][3]);
        acc[r][3] = fmaf(fv.z, w2.w, acc[r][3]);
        acc[r][3] = fmaf(fv.w, w3.w, acc[r][3]);
      }
    }
    __syncthreads();  // drains prefetch + protects buffer swap
  }

  // stage W2^T into freed lds_f (main loop done reading it)
  float* w2t = &lds_f[0][0];  // 1280 floats (fits: lds_f total 2048 floats)
  for (int i = tid; i < CDIM * NCLS; i += 256) {
    int k = i / NCLS, j = i - k * NCLS;
    w2t[j * 128 + k] = W2[i];
  }
  __syncthreads();

  // ---- layer 2, two 32-row halves through hbuf = full lds_w (16KB) ----
  float* hbuf = &lds_w[0][0];  // 4096 floats: both (freed) buffers
  float4 b1v = *(const float4*)(b1 + tc * 4);
#pragma unroll
  for (int half = 0; half < 2; ++half) {
    if ((tr >> 2) == half) {  // wave-uniform: waves 0,1 = half0; 2,3 = half1
      int ltr = tr & 3;
#pragma unroll
      for (int r = 0; r < 8; ++r) {
        float4 h;
        h.x = fmaxf(acc[r][0] + b1v.x, 0.f);
        h.y = fmaxf(acc[r][1] + b1v.y, 0.f);
        h.z = fmaxf(acc[r][2] + b1v.z, 0.f);
        h.w = fmaxf(acc[r][3] + b1v.w, 0.f);
        *(float4*)(hbuf + (ltr * 8 + r) * 128 + tc * 4) = h;
      }
    }
    __syncthreads();
    for (int o = tid; o < 32 * NCLS; o += 256) {
      int r = o / NCLS, j = o - r * NCLS;
      float s = b2[j];
      for (int i4 = 0; i4 < 32; ++i4) {
        int k4 = (i4 + tid) & 31;
        float4 hv = *(const float4*)(hbuf + r * 128 + k4 * 4);
        float4 wv2 = *(const float4*)(w2t + j * 128 + k4 * 4);
        s = fmaf(hv.x, wv2.x, s);
        s = fmaf(hv.y, wv2.y, s);
        s = fmaf(hv.z, wv2.z, s);
        s = fmaf(hv.w, wv2.w, s);
      }
      float heat = 1.0f / (1.0f + expf(-s));
      int gr = half * 32 + r;
      val_raw[(size_t)(row0 + gr) * PSTR + j] = heat;  // compact, coalesced
    }
    __syncthreads();
  }
}

// ---------------------------------------------------------------------------
// K2 (fused tail, NORMAL launch + software grid barriers): NMS+hist /
// threshold / collect / top-200+emit. 256 blocks x 1024 thr (16 waves/CU —
// fixes R6's 4-wave starvation). All selection math verbatim (bit-exact).
// ---------------------------------------------------------------------------
__global__ __launch_bounds__(TBLK) void k_tail(
    const float* __restrict__ val_raw, const int* __restrict__ idxs,
    const int* __restrict__ rowmap, float* __restrict__ val,
    unsigned int* __restrict__ hist, unsigned long long* __restrict__ sel,
    int* __restrict__ cnts, int* __restrict__ bar,
    const float* __restrict__ feat, const float* __restrict__ Wc,
    const float* __restrict__ bc, float* __restrict__ out) {
  __shared__ __align__(16) unsigned int lh[NB * HBINS];  // 32KB; sk later
  __shared__ unsigned int coarse[256];
  __shared__ unsigned int fine16[16];
  __shared__ int sT[NB], sCi[NB], lcnt[NB];
  __shared__ int spref[CTILE + 1];
  __shared__ unsigned long long winners[NPROP];
  __shared__ int wcls[NPROP], wrow[NPROP];

  const int tid = threadIdx.x;
  const int blk = blockIdx.x;

  // ---------------- Phase A: NMS + per-block LDS hist ----------------
  {
    uint4* l4 = (uint4*)lh;
    l4[tid] = make_uint4(0u, 0u, 0u, 0u);
    l4[tid + TBLK] = make_uint4(0u, 0u, 0u, 0u);
  }
  __syncthreads();
  const int g = tid >> 3;  // row slot in tile [0,128)
  const int n = tid & 7;   // neighbor slot
  // n -> (dy,dx): 0:(0,-1) 1:(0,1) 2:(-1,-1) 3:(-1,0) 4:(-1,1)
  //               5:(1,-1) 6:(1,0) 7:(1,1)
  const int dy = (n < 2) ? 0 : ((n < 5) ? -1 : 1);
  const int dx = (n < 2) ? (n * 2 - 1) : ((n < 5) ? (n - 3) : (n - 6));

  for (int t = blk; t < NTILE; t += TGRID) {
    const int row = t * 128 + g;
    const int bb = (row >= NPB) ? 1 : 0;
    const int y = idxs[row * 3 + 1];
    const int x = idxs[row * 3 + 2];
    const int pos = y * WG + x;
    const bool interior = (y > 0 && y < HG - 1 && x > 0 && x < WG - 1);
    // round 1: neighbor rowmap (interior guarantees pos+d in bounds)
    int nrow = -1;
    if (interior) nrow = rowmap[(size_t)bb * HW + pos + dy * WG + dx];
    const bool inb = ((unsigned)nrow < NROWS) && ((nrow >= NPB) == (bb == 1));
    const int safe = inb ? nrow : 0;
    // round 2: validation (unconditional, clamped index)
    const int y2 = idxs[safe * 3 + 1];
    const int x2 = idxs[safe * 3 + 2];
    const bool ok = inb && (y2 == y + dy) && (x2 == x + dx);
    // round 3: gather classes 0-7 (unconditional), mask to 0 if invalid
    float4 a = *(const float4*)(val_raw + (size_t)safe * PSTR);
    float4 b = *(const float4*)(val_raw + (size_t)safe * PSTR + 4);
    if (!ok) {
      a.x = a.y = a.z = a.w = 0.f;
      b.x = b.y = b.z = b.w = 0.f;
    }
#pragma unroll
    for (int m = 1; m <= 4; m <<= 1) {
      a.x = fmaxf(a.x, __shfl_xor(a.x, m));
      a.y = fmaxf(a.y, __shfl_xor(a.y, m));
      a.z = fmaxf(a.z, __shfl_xor(a.z, m));
      a.w = fmaxf(a.w, __shfl_xor(a.w, m));
      b.x = fmaxf(b.x, __shfl_xor(b.x, m));
      b.y = fmaxf(b.y, __shfl_xor(b.y, m));
      b.z = fmaxf(b.z, __shfl_xor(b.z, m));
      b.w = fmaxf(b.w, __shfl_xor(b.w, m));
    }
    if (n == 0) {
      const float* cbase = val_raw + (size_t)row * PSTR;
      float4 c0 = *(const float4*)(cbase + 0);
      float4 c1 = *(const float4*)(cbase + 4);
      float2 c89 = *(const float2*)(cbase + 8);
      float v[10];
      if (interior) {
        v[0] = (c0.x >= a.x) ? c0.x : 0.f;
        v[1] = (c0.y >= a.y) ? c0.y : 0.f;
        v[2] = (c0.z >= a.z) ? c0.z : 0.f;
        v[3] = (c0.w >= a.w) ? c0.w : 0.f;
        v[4] = (c1.x >= b.x) ? c1.x : 0.f;
        v[5] = (c1.y >= b.y) ? c1.y : 0.f;
        v[6] = (c1.z >= b.z) ? c1.z : 0.f;
        v[7] = (c1.w >= b.w) ? c1.w : 0.f;
      } else {
        v[0] = v[1] = v[2] = v[3] = v[4] = v[5] = v[6] = v[7] = 0.f;
      }
      v[8] = c89.x;
      v[9] = c89.y;
      float4 s0 = {v[0], v[1], v[2], v[3]};
      float4 s1 = {v[4], v[5], v[6], v[7]};
      float4 s2 = {v[8], v[9], 0.f, 0.f};
      *(float4*)(val + (size_t)row * PSTR + 0) = s0;
      *(float4*)(val + (size_t)row * PSTR + 4) = s1;
      *(float4*)(val + (size_t)row * PSTR + 8) = s2;
      unsigned int* lhb = lh + bb * HBINS;
#pragma unroll
      for (int c = 0; c < 10; ++c) {
        if (v[c] > 0.f) atomicAdd(&lhb[__float_as_uint(v[c]) >> 18], 1u);
      }
    }
  }
  __syncthreads();
  {  // flush once per block (fire-and-forget; ~4ns/op chains — cheap)
    uint4* l4 = (uint4*)lh;
    for (int i = tid; i < (NB * HBINS) / 4; i += TBLK) {
      uint4 q = l4[i];
      if (q.x) atomicAdd(&hist[i * 4 + 0], q.x);
      if (q.y) atomicAdd(&hist[i * 4 + 1], q.y);
      if (q.z) atomicAdd(&hist[i * 4 + 2], q.z);
      if (q.w) atomicAdd(&hist[i * 4 + 3], q.w);
    }
  }

  gbar(&bar[0]);  // hist + val complete

  // -------- Phase B: per-block redundant threshold (verbatim math) --------
  for (int bb = 0; bb < NB; ++bb) {
    if (tid == 0) {
      sCi[bb] = -1;
      sT[bb] = 0;
    }
    if (tid < 256) {
      const unsigned int* h = hist + (size_t)bb * HBINS;
      const uint4* h4 = (const uint4*)(h + tid * 16);
      unsigned int s = 0;
#pragma unroll
      for (int i = 0; i < 4; ++i) {
        uint4 q = h4[i];
        s += q.x + q.y + q.z + q.w;
      }
      coarse[tid] = s;
    }
    __syncthreads();
#pragma unroll
    for (int off = 1; off < 256; off <<= 1) {
      unsigned int vv = 0;
      if (tid < 256 && tid + off < 256) vv = coarse[tid + off];
      __syncthreads();
      if (tid < 256) coarse[tid] += vv;
      __syncthreads();
    }
    if (tid < 256 && coarse[tid] >= NPROP) atomicMax(&sCi[bb], tid);
    __syncthreads();
    const int ci = sCi[bb];
    if (ci >= 0) {
      if (tid < 16) fine16[tid] = hist[(size_t)bb * HBINS + ci * 16 + tid];
      __syncthreads();
      if (tid == 0) {
        unsigned int cum = (ci + 1 < 256) ? coarse[ci + 1] : 0u;
        int t = 15;
        for (; t > 0; --t) {
          unsigned int c = fine16[t];
          if (cum + c >= NPROP) break;
          cum += c;
        }
        sT[bb] = ci * 16 + t;
      }
    }
    __syncthreads();
  }

  // -------- Phase C: collect into per-(batch,tile) regions ----------------
  if (blk < CTILE) {
    if (tid < NB) lcnt[tid] = 0;
    __syncthreads();
    const int row = blk * TBLK + tid;
    const bool valid = row < NROWS;
    const int bb = (valid && row >= NPB) ? 1 : 0;
    const int T = sT[bb];
    float v[12];
    int pos = 0;
    if (valid) {
      *(float4*)(v + 0) = *(const float4*)(val + (size_t)row * PSTR + 0);
      *(float4*)(v + 4) = *(const float4*)(val + (size_t)row * PSTR + 4);
      *(float4*)(v + 8) = *(const float4*)(val + (size_t)row * PSTR + 8);
      pos = idxs[row * 3 + 1] * WG + idxs[row * 3 + 2];
    }
#pragma unroll
    for (int cl = 0; cl < 10; ++cl) {
      float vv = valid ? v[cl] : 0.f;
      unsigned int bits = __float_as_uint(vv);
      bool pred = (vv > 0.f) && ((int)(bits >> 18) >= T);
      if (pred) {
        int ls = atomicAdd(&lcnt[bb], 1);  // LDS, block-local
        if (ls < REG) {
          unsigned int gidx = (unsigned int)cl * HW + (unsigned int)pos;
          // key: heat bits desc, then smaller gidx (jax top_k tie-break)
          unsigned long long key =
              ((unsigned long long)bits << 32) | (unsigned long long)(~gidx);
          sel[((size_t)bb * CTILE + blk) * REG + ls] = key;
        }
      }
    }
    __syncthreads();
    if (tid < NB) {
      int c = lcnt[tid];
      cnts[tid * CTILE + blk] = (c < REG) ? c : REG;
    }
  }

  gbar(&bar[1]);  // sel + cnts complete

  // -------- Phase D: exact top-200 + partitioned emit (all blocks) --------
  const int b = blk / DPART;
  const int part = blk % DPART;
  if (tid == 0) {
    int acc = 0;
    for (int i = 0; i < CTILE; ++i) {
      spref[i] = acc;
      acc += cnts[b * CTILE + i];
    }
    spref[CTILE] = acc;
  }
  __syncthreads();
  int M = spref[CTILE];
  if (M > SEL_CAP) M = SEL_CAP;
  unsigned long long* sk = (unsigned long long*)lh;  // reuse 32KB LDS
  if (tid < CTILE) {
    int base = spref[tid];
    int c = spref[tid + 1] - base;
    const unsigned long long* src = sel + ((size_t)b * CTILE + tid) * REG;
    for (int j = 0; j < c; ++j) {
      int d = base + j;
      if (d < SEL_CAP) sk[d] = src[j];
    }
  }
  __syncthreads();
  for (int i = tid; i < M; i += TBLK) {
    unsigned long long key = sk[i];
    int rank = 0;
    for (int j = 0; j < M; ++j) rank += (sk[j] > key) ? 1 : 0;
    if (rank < NPROP) winners[rank] = key;
  }
  __syncthreads();
  if (tid < NPROP) {
    unsigned long long key = winners[tid];
    unsigned int gidx = ~((unsigned int)(key & 0xFFFFFFFFull));
    int cls = (int)(gidx / HW);
    int pos = (int)(gidx - (unsigned int)cls * HW);
    wcls[tid] = cls;
    wrow[tid] = rowmap[(size_t)b * HW + pos];
    if (part == 0) {
      int y = pos / WG, x = pos - y * WG;
      out[51200 + ((size_t)b * NPROP + tid) * 2 + 0] = (float)x;
      out[51200 + ((size_t)b * NPROP + tid) * 2 + 1] = (float)y;
      out[56000 + b * NPROP + tid] = (float)cls;
    }
  }
  __syncthreads();
  const int w = part * TBLK + tid;  // worker id within batch
  // qhs (B, NCLS, NPROP) at 52000
  for (int o = w; o < NCLS * NPROP; o += DPART * TBLK) {
    int j = o / NPROP, pp = o - j * NPROP;
    out[52000 + (size_t)b * NCLS * NPROP + o] = val[(size_t)wrow[pp] * PSTR + j];
  }
  // qf (B, C, NPROP) at 0
  for (int o = w; o < CDIM * NPROP; o += DPART * TBLK) {
    int c = o / NPROP, pp = o - c * NPROP;
    out[(size_t)b * CDIM * NPROP + o] =
        feat[(size_t)wrow[pp] * CDIM + c] + Wc[c * NCLS + wcls[pp]] + bc[c];
  }
}

// ---------------------------------------------------------------------------
// ws layout (bytes) — NO memsets; hist/cnts/bar zeroed by k_head block 0,
// rowmap validation-checked (no init):
//   [0)        hist    : B*4096*4 = 32,768
//   [32768)    rowmap  : B*HW*4   = 1,036,800   -> 1,069,568
//   [1069568)  cnts    : B*79*4   = 632         -> 1,070,200 (pad 1,070,208)
//   [1070208)  bar     : 2*4      = 8           -> 1,070,216 (pad 1,070,224)
//   [1070224)  sel     : B*79*96*8 = 121,344    -> 1,191,568
//   [1191568)  val_raw : 3,840,000              -> 5,031,568
//   [5031568)  val     : 3,840,000              -> 8,871,568
// total ~8.9 MB. Dispatches: 2 (k_head + fused k_tail, both normal).
// ---------------------------------------------------------------------------
extern "C" void kernel_launch(void* const* d_in, const int* in_sizes, int n_in,
                              void* d_out, int out_size, void* d_ws,
                              size_t ws_size, hipStream_t stream) {
  const float* feat = (const float*)d_in[0];
  const float* W1 = (const float*)d_in[1];
  const float* b1 = (const float*)d_in[2];
  const float* W2 = (const float*)d_in[3];
  const float* b2 = (const float*)d_in[4];
  const float* Wc = (const float*)d_in[5];
  const float* bc = (const float*)d_in[6];
  const int* idxs = (const int*)d_in[7];
  float* out = (float*)d_out;

  char* ws = (char*)d_ws;
  unsigned int* hist = (unsigned int*)(ws + 0);
  int* rowmap = (int*)(ws + 32768);
  int* cnts = (int*)(ws + 1069568);
  int* bar = (int*)(ws + 1070208);
  unsigned long long* sel = (unsigned long long*)(ws + 1070224);
  float* val_raw = (float*)(ws + 1191568);
  float* val = (float*)(ws + 5031568);

  k_head<<<NROWS / RPB, 256, 0, stream>>>(feat, W1, b1, W2, b2, idxs, val_raw,
                                          rowmap, hist, cnts, bar);
  k_tail<<<TGRID, TBLK, 0, stream>>>(val_raw, idxs, rowmap, val, hist, sel,
                                     cnts, bar, feat, Wc, bc, out);
}

// Round 11
// 173.482 us; speedup vs baseline: 1.7967x; 1.7967x over previous
//
#include <hip/hip_runtime.h>

#define HW 129600
#define WG 360
#define HG 360
#define NCLS 10
#define NPROP 200
#define CDIM 128
#define NROWS 80000
#define NB 2
#define NPB (NROWS / NB)    // rows are batch-sorted: row<40000 -> b=0
#define SEL_CAP 4096
#define HBINS 4096          // heat in (0,1]: (bits>>18) <= 4064
#define RPB 64              // rows per k_head block
#define PSTR 12             // row stride (floats): 10 classes + 2 pad, 48B
#define BPB 32              // k_final blocks per batch (emit parallelism)

// 48B all-zero row for invalid NMS neighbors: lives in module .rodata,
// never touched by workspace poisoning. No memset needed.
__device__ __align__(16) const float ZROW[12] = {0.f, 0.f, 0.f, 0.f, 0.f, 0.f,
                                                 0.f, 0.f, 0.f, 0.f, 0.f, 0.f};

// ---------------------------------------------------------------------------
// Async global->LDS DMA, 16B per lane; LDS dest wave-uniform base (m97/m104).
// ---------------------------------------------------------------------------
__device__ __forceinline__ void lds_cp16(float* l, const float* g) {
  __builtin_amdgcn_global_load_lds(
      (const __attribute__((address_space(1))) void*)g,
      (__attribute__((address_space(3))) void*)l, 16, 0, 0);
}

__device__ __forceinline__ float4 fmax4(float4 a, float4 b) {
  float4 r;
  r.x = fmaxf(a.x, b.x);
  r.y = fmaxf(a.y, b.y);
  r.z = fmaxf(a.z, b.z);
  r.w = fmaxf(a.w, b.w);
  return r;
}

// ---------------------------------------------------------------------------
// K1: fused MLP head. NEW: triple-buffered K-loop with COUNTED vmcnt
// (prefetch distance 2) — replaces __syncthreads' vmcnt(0) drain that
// stalled ~1100cy per K-step (compute cover 1024cy < HBM 2160cy; T4
// pattern: never drain to 0 in the main loop). stage(kt+2) is issued
// AFTER the barrier (all waves past reading buf[(kt+2)%3] = buf[(kt-1)%3],
// so the DMA write is WAR-safe). vmcnt(3) waits exactly the consumed
// buffer's 3 loads (in-order-oldest semantics, m135); barrier publishes
// every wave's DMA to the block. FMA order unchanged -> bit-exact heat.
// Block 0 zeroes hist + sel_cnt (consumers launch later in the stream).
// ---------------------------------------------------------------------------
__global__ __launch_bounds__(256, 4) void k_head(
    const float* __restrict__ feat, const float* __restrict__ W1,
    const float* __restrict__ b1, const float* __restrict__ W2,
    const float* __restrict__ b2, const int* __restrict__ idxs,
    float* __restrict__ val_raw, int* __restrict__ rowmap,
    unsigned int* __restrict__ hist, int* __restrict__ sel_cnt) {
  __shared__ __align__(16) float lds_w[3][16 * 128];  // 24KB: W1 chunks
  __shared__ __align__(16) float lds_f[3][RPB * 16];  // 12KB: f chunks
  const int tid = threadIdx.x;
  const int row0 = blockIdx.x * RPB;
  const int tc = tid & 31;
  const int tr = tid >> 5;
  const int wv = tid >> 6;  // wave id (uniform within wave)
  const int lane = tid & 63;

  auto stage = [&](int kt, int nb) {  // 3 global_load_lds per thread
#pragma unroll
    for (int c = 0; c < 2; ++c) {
      const int off = (wv * 2 + c) * 256;  // wave-uniform float offset
      lds_cp16(&lds_w[nb][off], W1 + kt * 2048 + off + lane * 4);
    }
    {
      const int off = wv * 256;
      const int fidx = off + lane * 4;
      const int r = fidx >> 4, kk = fidx & 15;
      lds_cp16(&lds_f[nb][off],
               feat + (size_t)(row0 + r) * CDIM + kt * 16 + kk);
    }
  };

  stage(0, 0);
  stage(1, 1);  // prefetch distance 2
  if (blockIdx.x == 0) {  // replaces hist/sel_cnt memset dispatches
    uint4* h4 = (uint4*)hist;
    for (int i = tid; i < (NB * HBINS) / 4; i += 256)
      h4[i] = make_uint4(0u, 0u, 0u, 0u);
    if (tid < 2) sel_cnt[tid] = 0;
  }
  if (tid < RPB) {
    int row = row0 + tid;
    int bb = idxs[row * 3 + 0];
    int yy = idxs[row * 3 + 1];
    int xx = idxs[row * 3 + 2];
    rowmap[(size_t)bb * HW + yy * WG + xx] = row;
  }

  float acc[8][4];
#pragma unroll
  for (int r = 0; r < 8; ++r)
#pragma unroll
    for (int c = 0; c < 4; ++c) acc[r][c] = 0.f;

#pragma unroll
  for (int kt = 0; kt < 8; ++kt) {
    const int cb = kt % 3;
    // wait the consumed buffer's 3 loads (oldest); keep the rest in flight
    if (kt < 7) {
      asm volatile("s_waitcnt vmcnt(3)" ::: "memory");
    } else {
      asm volatile("s_waitcnt vmcnt(0)" ::: "memory");
    }
    __builtin_amdgcn_sched_barrier(0);
    __builtin_amdgcn_s_barrier();  // publish all waves' DMA; free buf (kt-1)%3
    __builtin_amdgcn_sched_barrier(0);
    if (kt < 6) stage(kt + 2, (kt + 2) % 3);  // WAR-safe: after barrier
#pragma unroll
    for (int kg = 0; kg < 4; ++kg) {
      float4 w0 = *(const float4*)(&lds_w[cb][(kg * 4 + 0) * 128 + tc * 4]);
      float4 w1 = *(const float4*)(&lds_w[cb][(kg * 4 + 1) * 128 + tc * 4]);
      float4 w2 = *(const float4*)(&lds_w[cb][(kg * 4 + 2) * 128 + tc * 4]);
      float4 w3 = *(const float4*)(&lds_w[cb][(kg * 4 + 3) * 128 + tc * 4]);
#pragma unroll
      for (int r = 0; r < 8; ++r) {
        float4 fv = *(const float4*)(&lds_f[cb][(tr * 8 + r) * 16 + kg * 4]);
        acc[r][0] = fmaf(fv.x, w0.x, acc[r][0]);
        acc[r][0] = fmaf(fv.y, w1.x, acc[r][0]);
        acc[r][0] = fmaf(fv.z, w2.x, acc[r][0]);
        acc[r][0] = fmaf(fv.w, w3.x, acc[r][0]);
        acc[r][1] = fmaf(fv.x, w0.y, acc[r][1]);
        acc[r][1] = fmaf(fv.y, w1.y, acc[r][1]);
        acc[r][1] = fmaf(fv.z, w2.y, acc[r][1]);
        acc[r][1] = fmaf(fv.w, w3.y, acc[r][1]);
        acc[r][2] = fmaf(fv.x, w0.z, acc[r][2]);
        acc[r][2] = fmaf(fv.y, w1.z, acc[r][2]);
        acc[r][2] = fmaf(fv.z, w2.z, acc[r][2]);
        acc[r][2] = fmaf(fv.w, w3.z, acc[r][2]);
        acc[r][3] = fmaf(fv.x, w0.w, acc[r][3]);
        acc[r][3] = fmaf(fv.y, w1.w, acc[r][3]);
        acc[r][3] = fmaf(fv.z, w2.w, acc[r][3]);
        acc[r][3] = fmaf(fv.w, w3.w, acc[r][3]);
      }
    }
  }
  __syncthreads();  // all compute done before epilogue reuses buffers

  // stage W2^T into lds_f[0] (1280 floats <= 3072 available)
  float* w2t = &lds_f[0][0];
  for (int i = tid; i < CDIM * NCLS; i += 256) {
    int k = i / NCLS, j = i - k * NCLS;
    w2t[j * 128 + k] = W2[i];
  }
  __syncthreads();

  // ---- layer 2, two 32-row halves through hbuf = lds_w[0..] (16KB) ----
  float* hbuf = &lds_w[0][0];  // 4096 floats needed <= 6144 available
  float4 b1v = *(const float4*)(b1 + tc * 4);
#pragma unroll
  for (int half = 0; half < 2; ++half) {
    if ((tr >> 2) == half) {  // wave-uniform: waves 0,1 = half0; 2,3 = half1
      int ltr = tr & 3;
#pragma unroll
      for (int r = 0; r < 8; ++r) {
        float4 h;
        h.x = fmaxf(acc[r][0] + b1v.x, 0.f);
        h.y = fmaxf(acc[r][1] + b1v.y, 0.f);
        h.z = fmaxf(acc[r][2] + b1v.z, 0.f);
        h.w = fmaxf(acc[r][3] + b1v.w, 0.f);
        *(float4*)(hbuf + (ltr * 8 + r) * 128 + tc * 4) = h;
      }
    }
    __syncthreads();
    for (int o = tid; o < 32 * NCLS; o += 256) {
      int r = o / NCLS, j = o - r * NCLS;
      float s = b2[j];
      for (int i4 = 0; i4 < 32; ++i4) {
        int k4 = (i4 + tid) & 31;
        float4 hv = *(const float4*)(hbuf + r * 128 + k4 * 4);
        float4 wv2 = *(const float4*)(w2t + j * 128 + k4 * 4);
        s = fmaf(hv.x, wv2.x, s);
        s = fmaf(hv.y, wv2.y, s);
        s = fmaf(hv.z, wv2.z, s);
        s = fmaf(hv.w, wv2.w, s);
      }
      float heat = 1.0f / (1.0f + expf(-s));
      int gr = half * 32 + r;
      val_raw[(size_t)(row0 + gr) * PSTR + j] = heat;  // compact, coalesced
    }
    __syncthreads();
  }
}

// ---------------------------------------------------------------------------
// K2: sparse NMS + histogram via VALIDATED rowmap indirection (R5 verbatim —
// the proven-best tail; fusion attempts R6/R10 cost 100us+ in barriers).
// ---------------------------------------------------------------------------
__global__ __launch_bounds__(256) void k_hist(
    const float* __restrict__ val_raw, const int* __restrict__ idxs,
    const int* __restrict__ rowmap, float* __restrict__ val,
    unsigned int* __restrict__ hist) {
  __shared__ unsigned int lh[HBINS];
  const int tid = threadIdx.x;
  const int row = blockIdx.x * 256 + tid;
  const int blk_b = (blockIdx.x * 256 >= NPB) ? 1 : 0;
  for (int i = tid; i < HBINS; i += 256) lh[i] = 0;
  __syncthreads();

  float v[10];
  int bb = 0;
  const bool valid = row < NROWS;
  if (valid) {
    bb = (row >= NPB) ? 1 : 0;
    const int y = idxs[row * 3 + 1];
    const int x = idxs[row * 3 + 2];
    const int pos = y * WG + x;
    const float* cbase = val_raw + (size_t)row * PSTR;
    float4 c0 = *(const float4*)(cbase + 0);
    float4 c1 = *(const float4*)(cbase + 4);
    float2 c89 = *(const float2*)(cbase + 8);
    const bool interior = (y > 0 && y < HG - 1 && x > 0 && x < WG - 1);
    if (interior) {
      const int dyA[8] = {0, 0, -1, -1, -1, 1, 1, 1};
      const int dxA[8] = {-1, 1, -1, 0, 1, -1, 0, 1};
      float4 m0 = c0, m1 = c1;
      const int* rmb = rowmap + (size_t)bb * HW + pos;
#pragma unroll
      for (int n = 0; n < 8; ++n) {
        const int nrow = rmb[dyA[n] * WG + dxA[n]];
        bool ok =
            ((unsigned)nrow < NROWS) && ((nrow >= NPB) == (bb == 1));
        if (ok) {
          ok = (idxs[nrow * 3 + 1] == y + dyA[n]) &&
               (idxs[nrow * 3 + 2] == x + dxA[n]);
        }
        const float* p = ok ? (val_raw + (size_t)nrow * PSTR) : ZROW;
        m0 = fmax4(m0, *(const float4*)(p + 0));
        m1 = fmax4(m1, *(const float4*)(p + 4));
      }
      v[0] = (c0.x == m0.x) ? c0.x : 0.f;
      v[1] = (c0.y == m0.y) ? c0.y : 0.f;
      v[2] = (c0.z == m0.z) ? c0.z : 0.f;
      v[3] = (c0.w == m0.w) ? c0.w : 0.f;
      v[4] = (c1.x == m1.x) ? c1.x : 0.f;
      v[5] = (c1.y == m1.y) ? c1.y : 0.f;
      v[6] = (c1.z == m1.z) ? c1.z : 0.f;
      v[7] = (c1.w == m1.w) ? c1.w : 0.f;
    } else {
      v[0] = v[1] = v[2] = v[3] = v[4] = v[5] = v[6] = v[7] = 0.f;
    }
    v[8] = c89.x;
    v[9] = c89.y;
    // store suppressed vals (stride 12, 16B-aligned)
    float4 s0 = {v[0], v[1], v[2], v[3]};
    float4 s1 = {v[4], v[5], v[6], v[7]};
    float4 s2 = {v[8], v[9], 0.f, 0.f};
    *(float4*)(val + (size_t)row * PSTR + 0) = s0;
    *(float4*)(val + (size_t)row * PSTR + 4) = s1;
    *(float4*)(val + (size_t)row * PSTR + 8) = s2;
#pragma unroll
    for (int c = 0; c < 10; ++c) {
      if (v[c] > 0.f) {
        unsigned int bin = __float_as_uint(v[c]) >> 18;
        if (bb == blk_b)
          atomicAdd(&lh[bin], 1u);
        else  // only the batch-straddling block takes this path
          atomicAdd(&hist[(size_t)bb * HBINS + bin], 1u);
      }
    }
  }
  __syncthreads();
  unsigned int* gh = hist + (size_t)blk_b * HBINS;
  for (int i = tid; i < HBINS; i += 256) {
    unsigned int c = lh[i];
    if (c) atomicAdd(&gh[i], c);
  }
}

// ---------------------------------------------------------------------------
// K3: per-block threshold via parallel suffix-scan + compaction (R5 verbatim).
// ---------------------------------------------------------------------------
__global__ __launch_bounds__(256) void k_collect(
    const float* __restrict__ val, const int* __restrict__ idxs,
    const unsigned int* __restrict__ hist, unsigned long long* __restrict__ sel,
    int* __restrict__ sel_cnt) {
  __shared__ unsigned int coarse[256];
  __shared__ unsigned int fine16[16];
  __shared__ int sT[2];
  __shared__ int sCi[2];
  const int tid = threadIdx.x;
  for (int bb = 0; bb < NB; ++bb) {
    const unsigned int* h = hist + (size_t)bb * HBINS;
    const uint4* h4 = (const uint4*)(h + tid * 16);
    unsigned int s = 0;
#pragma unroll
    for (int i = 0; i < 4; ++i) {
      uint4 q = h4[i];
      s += q.x + q.y + q.z + q.w;
    }
    if (tid == 0) {
      sCi[bb] = -1;
      sT[bb] = 0;
    }
    coarse[tid] = s;
    __syncthreads();
    // in-place suffix scan: coarse[t] = sum_{i>=t} coarse_orig[i]
#pragma unroll
    for (int off = 1; off < 256; off <<= 1) {
      unsigned int vv = (tid + off < 256) ? coarse[tid + off] : 0u;
      __syncthreads();
      coarse[tid] += vv;
      __syncthreads();
    }
    if (coarse[tid] >= NPROP) atomicMax(&sCi[bb], tid);
    __syncthreads();
    const int ci = sCi[bb];
    if (ci >= 0) {
      if (tid < 16) fine16[tid] = h[ci * 16 + tid];
      __syncthreads();
      if (tid == 0) {
        unsigned int cum = (ci + 1 < 256) ? coarse[ci + 1] : 0u;
        int t = 15;
        for (; t > 0; --t) {
          unsigned int c = fine16[t];
          if (cum + c >= NPROP) break;
          cum += c;
        }
        sT[bb] = ci * 16 + t;
      }
    }
    __syncthreads();
  }
  const int row = blockIdx.x * 256 + tid;
  const bool valid = row < NROWS;
  const int bb = (valid && row >= NPB) ? 1 : 0;
  const int T = sT[bb];
  float v[12];
  int pos = 0;
  if (valid) {
    *(float4*)(v + 0) = *(const float4*)(val + (size_t)row * PSTR + 0);
    *(float4*)(v + 4) = *(const float4*)(val + (size_t)row * PSTR + 4);
    *(float4*)(v + 8) = *(const float4*)(val + (size_t)row * PSTR + 8);
    pos = idxs[row * 3 + 1] * WG + idxs[row * 3 + 2];
  }
  const int lane = tid & 63;
#pragma unroll
  for (int cl = 0; cl < 10; ++cl) {
    float vv = valid ? v[cl] : 0.f;
    unsigned int bits = __float_as_uint(vv);
    bool pred = (vv > 0.f) && ((int)(bits >> 18) >= T);
    unsigned long long m0 = __ballot(pred && (bb == 0));
    unsigned long long m1 = __ballot(pred && (bb == 1));
    if (pred) {
      unsigned long long mask = bb ? m1 : m0;
      int leader = __ffsll((unsigned long long)mask) - 1;
      int lb = __popcll(mask & ((1ull << lane) - 1ull));
      int base = 0;
      if (lane == leader) base = atomicAdd(&sel_cnt[bb], (int)__popcll(mask));
      base = __shfl(base, leader, 64);
      unsigned int gidx = (unsigned int)cl * HW + (unsigned int)pos;
      // key: heat bits desc, then smaller gidx first (jax top_k tie-break)
      unsigned long long key =
          ((unsigned long long)bits << 32) | (unsigned long long)(~gidx);
      int slot = base + lb;
      if (slot < SEL_CAP) sel[(size_t)bb * SEL_CAP + slot] = key;
    }
  }
}

// ---------------------------------------------------------------------------
// K4: exact top-200 by rank-counting, 32 blocks/batch partitioned emit
// (R5 verbatim).
// ---------------------------------------------------------------------------
__global__ __launch_bounds__(256) void k_final(
    const unsigned long long* __restrict__ sel, const int* __restrict__ sel_cnt,
    const float* __restrict__ val, const int* __restrict__ rowmap,
    const float* __restrict__ feat, const float* __restrict__ Wc,
    const float* __restrict__ bc, float* __restrict__ out) {
  __shared__ unsigned long long sk[SEL_CAP];
  __shared__ unsigned long long winners[NPROP];
  __shared__ int wcls[NPROP];
  __shared__ int wrow[NPROP];
  const int b = blockIdx.x / BPB;
  const int part = blockIdx.x % BPB;
  const int tid = threadIdx.x;
  int M = sel_cnt[b];
  if (M > SEL_CAP) M = SEL_CAP;
  for (int i = tid; i < M; i += 256) sk[i] = sel[(size_t)b * SEL_CAP + i];
  __syncthreads();
  for (int i = tid; i < M; i += 256) {
    unsigned long long key = sk[i];
    int rank = 0;
    for (int j = 0; j < M; ++j) rank += (sk[j] > key) ? 1 : 0;
    if (rank < NPROP) winners[rank] = key;
  }
  __syncthreads();
  if (tid < NPROP) {
    unsigned long long key = winners[tid];
    unsigned int gidx = ~((unsigned int)(key & 0xFFFFFFFFull));
    int cls = (int)(gidx / HW);
    int pos = (int)(gidx - (unsigned int)cls * HW);
    wcls[tid] = cls;
    wrow[tid] = rowmap[(size_t)b * HW + pos];
    if (part == 0) {
      int y = pos / WG, x = pos - y * WG;
      out[51200 + ((size_t)b * NPROP + tid) * 2 + 0] = (float)x;
      out[51200 + ((size_t)b * NPROP + tid) * 2 + 1] = (float)y;
      out[56000 + b * NPROP + tid] = (float)cls;
    }
  }
  __syncthreads();
  // qhs (B, NCLS, NPROP) at 52000 — partitioned strided slices
  for (int o = part * 256 + tid; o < NCLS * NPROP; o += BPB * 256) {
    int j = o / NPROP, pp = o - j * NPROP;
    out[52000 + (size_t)b * NCLS * NPROP + o] = val[(size_t)wrow[pp] * PSTR + j];
  }
  // qf (B, C, NPROP) at 0 — partitioned strided slices
  for (int o = part * 256 + tid; o < CDIM * NPROP; o += BPB * 256) {
    int c = o / NPROP, pp = o - c * NPROP;
    out[(size_t)b * CDIM * NPROP + o] =
        feat[(size_t)wrow[pp] * CDIM + c] + Wc[c * NCLS + wcls[pp]] + bc[c];
  }
}

// ---------------------------------------------------------------------------
// ws layout (bytes) — NO memsets; hist/sel_cnt zeroed by k_head block 0,
// rowmap is validation-checked (no init), ZROW is module .rodata:
//   [0)        hist    : B*4096*4 = 32,768
//   [32768)    rowmap  : B*HW*4   = 1,036,800  -> ends 1,069,568
//   [1069568)  sel     : B*4096*8 = 65,536     -> ends 1,135,104
//   [1135104)  cnts    : sel_cnt[2] (16B)      -> 1,135,120
//   [1135120)  val_raw : 80000*12*4 = 3,840,000 -> 4,975,120
//   [4975120)  val     : 80000*12*4 = 3,840,000 -> 8,815,120
// total ~8.8 MB. Dispatches: 4 (R5 structure — fusion refuted twice).
// ---------------------------------------------------------------------------
extern "C" void kernel_launch(void* const* d_in, const int* in_sizes, int n_in,
                              void* d_out, int out_size, void* d_ws,
                              size_t ws_size, hipStream_t stream) {
  const float* feat = (const float*)d_in[0];
  const float* W1 = (const float*)d_in[1];
  const float* b1 = (const float*)d_in[2];
  const float* W2 = (const float*)d_in[3];
  const float* b2 = (const float*)d_in[4];
  const float* Wc = (const float*)d_in[5];
  const float* bc = (const float*)d_in[6];
  const int* idxs = (const int*)d_in[7];
  float* out = (float*)d_out;

  char* ws = (char*)d_ws;
  unsigned int* hist = (unsigned int*)(ws + 0);
  int* rowmap = (int*)(ws + 32768);
  unsigned long long* sel = (unsigned long long*)(ws + 1069568);
  int* sel_cnt = (int*)(ws + 1135104);
  float* val_raw = (float*)(ws + 1135120);
  float* val = (float*)(ws + 4975120);

  k_head<<<NROWS / RPB, 256, 0, stream>>>(feat, W1, b1, W2, b2, idxs, val_raw,
                                          rowmap, hist, sel_cnt);
  k_hist<<<(NROWS + 255) / 256, 256, 0, stream>>>(val_raw, idxs, rowmap, val,
                                                  hist);
  k_collect<<<(NROWS + 255) / 256, 256, 0, stream>>>(val, idxs, hist, sel,
                                                     sel_cnt);
  k_final<<<NB * BPB, 256, 0, stream>>>(sel, sel_cnt, val, rowmap, feat, Wc, bc,
                                        out);
}